// Round 1
// baseline (193.998 us; speedup 1.0000x reference)
//
#include <hip/hip_runtime.h>
#include <hip/hip_bf16.h>

// LinearAttention on MI355X (gfx950), bf16-MFMA pipeline.
// final[b] = W2[b] @ q[b] + b_out, W2 folded from w_out and per-head contexts.

typedef __attribute__((ext_vector_type(8))) __bf16 bf16x8;
typedef __attribute__((ext_vector_type(4))) float f32x4;
typedef __attribute__((ext_vector_type(8))) unsigned short u16x8;

__device__ __forceinline__ unsigned short f2b(float f) {
  unsigned int u = __builtin_bit_cast(unsigned int, f);
  unsigned int r = (u + 0x7FFFu + ((u >> 16) & 1u)) >> 16;  // RNE
  return (unsigned short)r;
}
__device__ __forceinline__ float b2f(unsigned short h) {
  unsigned int u = ((unsigned int)h) << 16;
  return __builtin_bit_cast(float, u);
}

// ---------------- kernel 0a: w_qkv fp32 -> bf16 ----------------
__global__ __launch_bounds__(256) void wconv_kernel(const float* __restrict__ w,
                                                    unsigned short* __restrict__ wb) {
  int i = (blockIdx.x * 256 + threadIdx.x) * 4;
  #pragma unroll
  for (int j = 0; j < 4; ++j) wb[i + j] = f2b(w[i + j]);
}

// ---------------- kernel 0b: x (b,c,n) fp32 -> xT (b,n,c) bf16 ----------------
__global__ __launch_bounds__(256) void transpose_x_kernel(const float* __restrict__ x,
                                                          unsigned short* __restrict__ xT) {
  __shared__ unsigned short tile[64][65];
  const int b = blockIdx.z, ct = blockIdx.y, nt = blockIdx.x;
  const int c0 = ct * 64, n0 = nt * 64;
  const int tc = threadIdx.x & 63, tr = threadIdx.x >> 6;
  const float* xp = x + ((long)b * 512 + c0) * 4096 + n0;
  #pragma unroll
  for (int i = 0; i < 16; ++i) {
    int row = tr * 16 + i;                       // c-local
    tile[tc][row] = f2b(xp[(long)row * 4096 + tc]);  // tile[n][c]
  }
  __syncthreads();
  unsigned short* xtp = xT + ((long)b * 4096 + n0) * 512 + c0;
  #pragma unroll
  for (int i = 0; i < 16; ++i) {
    int row = tr * 16 + i;                       // n-local
    xtp[(long)row * 512 + tc] = tile[row][tc];
  }
}

// ---------------- kernel 2b: q region (b, e, n) bf16 -> qT (b, n, e) bf16 ----------------
__global__ __launch_bounds__(256) void transpose_q_kernel(const unsigned short* __restrict__ qkv,
                                                          unsigned short* __restrict__ qT) {
  __shared__ unsigned short tile[64][65];
  const int b = blockIdx.z, et = blockIdx.y, nt = blockIdx.x;
  const int e0 = et * 64, n0 = nt * 64;
  const int tc = threadIdx.x & 63, tr = threadIdx.x >> 6;
  const unsigned short* qp = qkv + ((long)b * 1536 + e0) * 4096 + n0;
  #pragma unroll
  for (int i = 0; i < 16; ++i) {
    int row = tr * 16 + i;                       // e-local
    tile[tc][row] = qp[(long)row * 4096 + tc];   // tile[n][e]
  }
  __syncthreads();
  unsigned short* qtp = qT + ((long)b * 4096 + n0) * 512 + e0;
  #pragma unroll
  for (int i = 0; i < 16; ++i) {
    int row = tr * 16 + i;                       // n-local
    qtp[(long)row * 512 + tc] = tile[row][tc];
  }
}

// ---------------- GEMM: C[b] = A[b] (MxK bf16) @ BT[b]^T (NxK bf16) ----------------
// 128x128 tile, BK=64, 4 waves (2x2 of 64x64), 16x16x32 bf16 MFMA.
// global_load_lds 16B staging, linear LDS dest + inverse-swizzled source,
// swizzled ds_read_b128 (granule ^= row&7) -> conflict-free fragment reads.
__global__ __launch_bounds__(256) void gemm128_bt(
    const unsigned short* __restrict__ A, long strideA,
    const unsigned short* __restrict__ BT, long strideBT,
    void* __restrict__ Cout, long strideC,
    const float* __restrict__ bias) {
  constexpr int K = 512;
  constexpr int N = 4096;
  const int b = blockIdx.z;
  const int m0 = blockIdx.y * 128;
  const int n0 = blockIdx.x * 128;
  const unsigned short* Ab = A + (long)b * strideA;
  const unsigned short* Bb = BT + (long)b * strideBT;

  __shared__ unsigned short lds[2 * 128 * 64];  // A tile 16KB, B tile 16KB
  char* ldsc = (char*)lds;

  const int tid = threadIdx.x;
  const int wave = tid >> 6;
  const int lane = tid & 63;
  const int wr = wave >> 1;
  const int wc = wave & 1;

  f32x4 acc[4][4];
  const f32x4 zero = {0.f, 0.f, 0.f, 0.f};
  #pragma unroll
  for (int i = 0; i < 4; ++i)
    #pragma unroll
    for (int j = 0; j < 4; ++j) acc[i][j] = zero;

  for (int kt = 0; kt < K; kt += 64) {
    // stage A(128x64) + B(128x64) bf16 into LDS
    #pragma unroll
    for (int q = 0; q < 4; ++q) {
      unsigned base = q * 4096 + wave * 1024;
      unsigned D = base + lane * 16;    // dest byte this lane's 16B lands at
      unsigned row = D >> 7;            // 128B per row
      unsigned g = (D >> 4) & 7;        // physical granule
      unsigned gl = g ^ (row & 7);      // logical granule (inverse swizzle)
      const unsigned short* srcA = Ab + (long)(m0 + row) * K + kt + gl * 8;
      __builtin_amdgcn_global_load_lds(
          (const __attribute__((address_space(1))) unsigned int*)srcA,
          (__attribute__((address_space(3))) unsigned int*)(ldsc + base), 16, 0, 0);
      const unsigned short* srcB = Bb + (long)(n0 + row) * K + kt + gl * 8;
      __builtin_amdgcn_global_load_lds(
          (const __attribute__((address_space(1))) unsigned int*)srcB,
          (__attribute__((address_space(3))) unsigned int*)(ldsc + 16384 + base), 16, 0, 0);
    }
    __syncthreads();

    bf16x8 af[2][4], bfr[2][4];
    #pragma unroll
    for (int ks = 0; ks < 2; ++ks) {
      #pragma unroll
      for (int mi = 0; mi < 4; ++mi) {
        unsigned row = wr * 64 + mi * 16 + (lane & 15);
        unsigned g = ((unsigned)(ks * 4 + (lane >> 4))) ^ (row & 7);
        af[ks][mi] = *(const bf16x8*)(ldsc + row * 128 + g * 16);
      }
      #pragma unroll
      for (int ni = 0; ni < 4; ++ni) {
        unsigned row = wc * 64 + ni * 16 + (lane & 15);
        unsigned g = ((unsigned)(ks * 4 + (lane >> 4))) ^ (row & 7);
        bfr[ks][ni] = *(const bf16x8*)(ldsc + 16384 + row * 128 + g * 16);
      }
    }
    #pragma unroll
    for (int ks = 0; ks < 2; ++ks)
      #pragma unroll
      for (int mi = 0; mi < 4; ++mi)
        #pragma unroll
        for (int ni = 0; ni < 4; ++ni)
          acc[mi][ni] = __builtin_amdgcn_mfma_f32_16x16x32_bf16(
              af[ks][mi], bfr[ks][ni], acc[mi][ni], 0, 0, 0);
    __syncthreads();
  }

  const int r0 = (lane >> 4) * 4;
  const int cn = lane & 15;
  if (bias != nullptr) {
    float* C = (float*)Cout + (long)b * strideC;
    #pragma unroll
    for (int mi = 0; mi < 4; ++mi) {
      int o = m0 + wr * 64 + mi * 16 + r0;
      #pragma unroll
      for (int ni = 0; ni < 4; ++ni) {
        int n = n0 + wc * 64 + ni * 16 + cn;
        #pragma unroll
        for (int r = 0; r < 4; ++r)
          C[(long)(o + r) * N + n] = acc[mi][ni][r] + bias[o + r];
      }
    }
  } else {
    unsigned short* C = (unsigned short*)Cout + (long)b * strideC;
    #pragma unroll
    for (int mi = 0; mi < 4; ++mi) {
      int o = m0 + wr * 64 + mi * 16 + r0;
      #pragma unroll
      for (int ni = 0; ni < 4; ++ni) {
        int n = n0 + wc * 64 + ni * 16 + cn;
        #pragma unroll
        for (int r = 0; r < 4; ++r)
          C[(long)(o + r) * N + n] = f2b(acc[mi][ni][r]);
      }
    }
  }
}

// ---------------- kernel 2: softmax over n on k region, in place (bf16) ----------------
__global__ __launch_bounds__(256) void softmax_k_kernel(unsigned short* __restrict__ qkv) {
  const int row = blockIdx.x;          // 0..4095 = b*512 + d
  const int b = row >> 9, d = row & 511;
  unsigned short* kp = qkv + ((long)b * 1536 + 512 + d) * 4096;
  const int tid = threadIdx.x, wave = tid >> 6, lane = tid & 63;
  __shared__ float red[8];

  float v[16];
  u16x8 l0 = *(const u16x8*)(kp + tid * 8);
  u16x8 l1 = *(const u16x8*)(kp + 2048 + tid * 8);
  #pragma unroll
  for (int j = 0; j < 8; ++j) { v[j] = b2f(l0[j]); v[8 + j] = b2f(l1[j]); }

  float m = v[0];
  #pragma unroll
  for (int j = 1; j < 16; ++j) m = fmaxf(m, v[j]);
  #pragma unroll
  for (int off = 32; off > 0; off >>= 1) m = fmaxf(m, __shfl_xor(m, off));
  if (lane == 0) red[wave] = m;
  __syncthreads();
  m = fmaxf(fmaxf(red[0], red[1]), fmaxf(red[2], red[3]));

  float s = 0.f;
  #pragma unroll
  for (int j = 0; j < 16; ++j) { v[j] = __expf(v[j] - m); s += v[j]; }
  #pragma unroll
  for (int off = 32; off > 0; off >>= 1) s += __shfl_xor(s, off);
  if (lane == 0) red[4 + wave] = s;
  __syncthreads();
  s = red[4] + red[5] + red[6] + red[7];
  float inv = 1.0f / s;

  u16x8 o0, o1;
  #pragma unroll
  for (int j = 0; j < 8; ++j) { o0[j] = f2b(v[j] * inv); o1[j] = f2b(v[8 + j] * inv); }
  *(u16x8*)(kp + tid * 8) = o0;
  *(u16x8*)(kp + 2048 + tid * 8) = o1;
}

// ---------------- kernel 3: per-(b,h) context = k_sm @ v^T (64x64, K=4096) ----------------
__global__ __launch_bounds__(256) void context_kernel(const unsigned short* __restrict__ qkv,
                                                      float* __restrict__ ctx) {
  const int bh = blockIdx.x, b = bh >> 3, h = bh & 7;
  const unsigned short* Kp = qkv + ((long)b * 1536 + 512 + h * 64) * 4096;
  const unsigned short* Vp = qkv + ((long)b * 1536 + 1024 + h * 64) * 4096;
  const int tid = threadIdx.x, wave = tid >> 6, lane = tid & 63;

  f32x4 acc[4][4];
  const f32x4 zero = {0.f, 0.f, 0.f, 0.f};
  #pragma unroll
  for (int i = 0; i < 4; ++i)
    #pragma unroll
    for (int j = 0; j < 4; ++j) acc[i][j] = zero;

  const int kbeg = wave * 1024;
  for (int k0 = kbeg; k0 < kbeg + 1024; k0 += 32) {
    const int kc = k0 + (lane >> 4) * 8;
    bf16x8 a[4], bv[4];
    #pragma unroll
    for (int mi = 0; mi < 4; ++mi)
      a[mi] = *(const bf16x8*)(Kp + (long)(mi * 16 + (lane & 15)) * 4096 + kc);
    #pragma unroll
    for (int ni = 0; ni < 4; ++ni)
      bv[ni] = *(const bf16x8*)(Vp + (long)(ni * 16 + (lane & 15)) * 4096 + kc);
    #pragma unroll
    for (int mi = 0; mi < 4; ++mi)
      #pragma unroll
      for (int ni = 0; ni < 4; ++ni)
        acc[mi][ni] = __builtin_amdgcn_mfma_f32_16x16x32_bf16(a[mi], bv[ni], acc[mi][ni], 0, 0, 0);
  }

  __shared__ float part[4][64][64];  // 64KB
  #pragma unroll
  for (int mi = 0; mi < 4; ++mi)
    #pragma unroll
    for (int ni = 0; ni < 4; ++ni)
      #pragma unroll
      for (int r = 0; r < 4; ++r)
        part[wave][mi * 16 + (lane >> 4) * 4 + r][ni * 16 + (lane & 15)] = acc[mi][ni][r];
  __syncthreads();
  float* cp = ctx + (long)bh * 4096;
  for (int i = tid; i < 4096; i += 256) {
    int dd = i >> 6, ee = i & 63;
    cp[i] = part[0][dd][ee] + part[1][dd][ee] + part[2][dd][ee] + part[3][dd][ee];
  }
}

// ---------------- kernel 3b: W2[b][c][h*64+d] = sum_e w_out[c][h*64+e]*ctx[b,h][d][e] ----------------
__global__ __launch_bounds__(256) void w2_kernel(const float* __restrict__ ctx,
                                                 const float* __restrict__ w_out,
                                                 unsigned short* __restrict__ W2) {
  const int cc = blockIdx.x, bh = blockIdx.y, b = bh >> 3, h = bh & 7;
  __shared__ float cs[64][65];
  const int tid = threadIdx.x;
  for (int i = tid; i < 4096; i += 256) cs[i >> 6][i & 63] = ctx[(long)bh * 4096 + i];
  __syncthreads();
  const int c = cc * 64 + (tid >> 2);
  const int d0 = (tid & 3) * 16;
  float wrow[64];
  const float* wp = w_out + (long)c * 512 + h * 64;
  #pragma unroll
  for (int e = 0; e < 64; ++e) wrow[e] = wp[e];
  unsigned short* W2p = W2 + ((long)b * 512 + c) * 512 + h * 64;
  #pragma unroll 4
  for (int dd = 0; dd < 16; ++dd) {
    float s = 0.f;
    #pragma unroll
    for (int e = 0; e < 64; ++e) s = fmaf(wrow[e], cs[d0 + dd][e], s);
    W2p[d0 + dd] = f2b(s);
  }
}

extern "C" void kernel_launch(void* const* d_in, const int* in_sizes, int n_in,
                              void* d_out, int out_size, void* d_ws, size_t ws_size,
                              hipStream_t stream) {
  const float* x     = (const float*)d_in[0];   // (8, 512, 64, 64)
  const float* w_qkv = (const float*)d_in[1];   // (1536, 512)
  const float* w_out = (const float*)d_in[2];   // (512, 512)
  const float* b_out = (const float*)d_in[3];   // (512,)

  char* ws = (char*)d_ws;
  unsigned short* qkv = (unsigned short*)ws;                  // 8*1536*4096*2 = 100663296 B
  unsigned short* xT  = (unsigned short*)(ws + 100663296);    // 8*4096*512*2 = 33554432 B
  unsigned short* qT  = xT;                                   // reuse (xT dead after GEMM1)
  unsigned short* wqb = (unsigned short*)(ws + 134217728);    // 1536*512*2 = 1572864 B
  float*          ctx = (float*)(ws + 135790592);             // 64*64*64*4 = 1048576 B
  unsigned short* W2  = (unsigned short*)(ws + 136839168);    // 8*512*512*2 = 4194304 B

  wconv_kernel<<<dim3(768), dim3(256), 0, stream>>>(w_qkv, wqb);
  transpose_x_kernel<<<dim3(64, 8, 8), dim3(256), 0, stream>>>(x, xT);
  // qkv = w_qkv @ x  (per batch: 1536x512 @ 512x4096)
  gemm128_bt<<<dim3(32, 12, 8), dim3(256), 0, stream>>>(
      wqb, 0L, xT, (long)4096 * 512, (void*)qkv, (long)1536 * 4096, (const float*)nullptr);
  softmax_k_kernel<<<dim3(4096), dim3(256), 0, stream>>>(qkv);
  transpose_q_kernel<<<dim3(64, 8, 8), dim3(256), 0, stream>>>(qkv, qT);
  context_kernel<<<dim3(64), dim3(256), 0, stream>>>(qkv, ctx);
  w2_kernel<<<dim3(8, 64), dim3(256), 0, stream>>>(ctx, w_out, W2);
  // out = W2 @ q + bias  (per batch: 512x512 @ 512x4096)
  gemm128_bt<<<dim3(32, 4, 8), dim3(256), 0, stream>>>(
      W2, (long)512 * 512, qT, (long)4096 * 512, d_out, (long)512 * 4096, b_out);
}

// Round 2
// 166.290 us; speedup vs baseline: 1.1666x; 1.1666x over previous
//
#include <hip/hip_runtime.h>
#include <hip/hip_bf16.h>

// LinearAttention on MI355X (gfx950), bf16-MFMA pipeline, round 2.
// Algebra: final[b] = (W2[b] @ Wq) @ x[b] + b_out, where
//   W2[b][c][h*64+d] = sum_e w_out[c][h*64+e] * ctx[b,h][d][e]
//   ctx[b,h] = softmax_rows(k) @ v^T   (k,v = rows 512..1536 of w_qkv @ x)
// q is never materialized: W3[b] = W2[b] @ Wq folds it into the weights.

typedef __attribute__((ext_vector_type(8))) __bf16 bf16x8;
typedef __attribute__((ext_vector_type(4))) float f32x4;
typedef __attribute__((ext_vector_type(8))) unsigned short u16x8;

__device__ __forceinline__ unsigned short f2b(float f) {
  unsigned int u = __builtin_bit_cast(unsigned int, f);
  unsigned int r = (u + 0x7FFFu + ((u >> 16) & 1u)) >> 16;  // RNE
  return (unsigned short)r;
}
__device__ __forceinline__ float b2f(unsigned short h) {
  unsigned int u = ((unsigned int)h) << 16;
  return __builtin_bit_cast(float, u);
}

// ---------------- prep: w_qkv rows 512..1536 fp32 -> bf16 (k,v weights) ----------------
__global__ __launch_bounds__(256) void prep_wkv_kernel(const float* __restrict__ w,
                                                       unsigned short* __restrict__ wkv) {
  int i = (blockIdx.x * 256 + threadIdx.x) * 4;
  const float* src = w + 512 * 512;
  #pragma unroll
  for (int j = 0; j < 4; ++j) wkv[i + j] = f2b(src[i + j]);
}

// ---------------- prep: WqT[c][o] = w_qkv[o][c], o<512, fp32 -> bf16 ----------------
__global__ __launch_bounds__(256) void prep_wqT_kernel(const float* __restrict__ w,
                                                       unsigned short* __restrict__ WqT) {
  __shared__ unsigned short tile[64][65];
  const int ct = blockIdx.x, ot = blockIdx.y;
  const int c0 = ct * 64, o0 = ot * 64;
  const int tc = threadIdx.x & 63, tr = threadIdx.x >> 6;
  #pragma unroll
  for (int i = 0; i < 16; ++i) {
    int row = tr * 16 + i;                                  // o-local
    tile[tc][row] = f2b(w[(long)(o0 + row) * 512 + c0 + tc]);  // tile[c][o]
  }
  __syncthreads();
  #pragma unroll
  for (int i = 0; i < 16; ++i) {
    int row = tr * 16 + i;                                  // c-local
    WqT[(long)(c0 + row) * 512 + o0 + tc] = tile[row][tc];
  }
}

// ---------------- x (b,c,n) fp32 -> xT (b,n,c) bf16 ----------------
__global__ __launch_bounds__(256) void transpose_x_kernel(const float* __restrict__ x,
                                                          unsigned short* __restrict__ xT) {
  __shared__ unsigned short tile[64][65];
  const int b = blockIdx.z, ct = blockIdx.y, nt = blockIdx.x;
  const int c0 = ct * 64, n0 = nt * 64;
  const int tc = threadIdx.x & 63, tr = threadIdx.x >> 6;
  const float* xp = x + ((long)b * 512 + c0) * 4096 + n0;
  #pragma unroll
  for (int i = 0; i < 16; ++i) {
    int row = tr * 16 + i;                       // c-local
    tile[tc][row] = f2b(xp[(long)row * 4096 + tc]);  // tile[n][c]
  }
  __syncthreads();
  unsigned short* xtp = xT + ((long)b * 4096 + n0) * 512 + c0;
  #pragma unroll
  for (int i = 0; i < 16; ++i) {
    int row = tr * 16 + i;                       // n-local
    xtp[(long)row * 512 + tc] = tile[row][tc];
  }
}

// ---------------- GEMM: C[b] = A[b] (MxK=512 bf16) @ BT[b]^T (NxK bf16) ----------------
// 128x128 tile, BK=64, 4 waves (2x2 of 64x64), 16x16x32 bf16 MFMA.
// global_load_lds 16B staging, linear LDS dest + inverse-swizzled source,
// swizzled ds_read_b128 (granule ^= row&7) -> conflict-free fragment reads.
__global__ __launch_bounds__(256) void gemm128_bt(
    const unsigned short* __restrict__ A, long strideA,
    const unsigned short* __restrict__ BT, long strideBT,
    void* __restrict__ Cout, long strideC, int ldc,
    const float* __restrict__ bias) {
  constexpr int K = 512;
  const int b = blockIdx.z;
  const int m0 = blockIdx.y * 128;
  const int n0 = blockIdx.x * 128;
  const unsigned short* Ab = A + (long)b * strideA;
  const unsigned short* Bb = BT + (long)b * strideBT;

  __shared__ unsigned short lds[2 * 128 * 64];  // A tile 16KB, B tile 16KB
  char* ldsc = (char*)lds;

  const int tid = threadIdx.x;
  const int wave = tid >> 6;
  const int lane = tid & 63;
  const int wr = wave >> 1;
  const int wc = wave & 1;

  f32x4 acc[4][4];
  const f32x4 zero = {0.f, 0.f, 0.f, 0.f};
  #pragma unroll
  for (int i = 0; i < 4; ++i)
    #pragma unroll
    for (int j = 0; j < 4; ++j) acc[i][j] = zero;

  for (int kt = 0; kt < K; kt += 64) {
    #pragma unroll
    for (int q = 0; q < 4; ++q) {
      unsigned base = q * 4096 + wave * 1024;
      unsigned D = base + lane * 16;    // dest byte this lane's 16B lands at
      unsigned row = D >> 7;            // 128B per row
      unsigned g = (D >> 4) & 7;        // physical granule
      unsigned gl = g ^ (row & 7);      // logical granule (inverse swizzle)
      const unsigned short* srcA = Ab + (long)(m0 + row) * K + kt + gl * 8;
      __builtin_amdgcn_global_load_lds(
          (const __attribute__((address_space(1))) unsigned int*)srcA,
          (__attribute__((address_space(3))) unsigned int*)(ldsc + base), 16, 0, 0);
      const unsigned short* srcB = Bb + (long)(n0 + row) * K + kt + gl * 8;
      __builtin_amdgcn_global_load_lds(
          (const __attribute__((address_space(1))) unsigned int*)srcB,
          (__attribute__((address_space(3))) unsigned int*)(ldsc + 16384 + base), 16, 0, 0);
    }
    __syncthreads();

    bf16x8 af[2][4], bfr[2][4];
    #pragma unroll
    for (int ks = 0; ks < 2; ++ks) {
      #pragma unroll
      for (int mi = 0; mi < 4; ++mi) {
        unsigned row = wr * 64 + mi * 16 + (lane & 15);
        unsigned g = ((unsigned)(ks * 4 + (lane >> 4))) ^ (row & 7);
        af[ks][mi] = *(const bf16x8*)(ldsc + row * 128 + g * 16);
      }
      #pragma unroll
      for (int ni = 0; ni < 4; ++ni) {
        unsigned row = wc * 64 + ni * 16 + (lane & 15);
        unsigned g = ((unsigned)(ks * 4 + (lane >> 4))) ^ (row & 7);
        bfr[ks][ni] = *(const bf16x8*)(ldsc + 16384 + row * 128 + g * 16);
      }
    }
    #pragma unroll
    for (int ks = 0; ks < 2; ++ks)
      #pragma unroll
      for (int mi = 0; mi < 4; ++mi)
        #pragma unroll
        for (int ni = 0; ni < 4; ++ni)
          acc[mi][ni] = __builtin_amdgcn_mfma_f32_16x16x32_bf16(
              af[ks][mi], bfr[ks][ni], acc[mi][ni], 0, 0, 0);
    __syncthreads();
  }

  const int r0 = (lane >> 4) * 4;
  const int cn = lane & 15;
  if (bias != nullptr) {
    float* C = (float*)Cout + (long)b * strideC;
    #pragma unroll
    for (int mi = 0; mi < 4; ++mi) {
      int o = m0 + wr * 64 + mi * 16 + r0;
      #pragma unroll
      for (int ni = 0; ni < 4; ++ni) {
        int n = n0 + wc * 64 + ni * 16 + cn;
        #pragma unroll
        for (int r = 0; r < 4; ++r)
          C[(long)(o + r) * ldc + n] = acc[mi][ni][r] + bias[o + r];
      }
    }
  } else {
    unsigned short* C = (unsigned short*)Cout + (long)b * strideC;
    #pragma unroll
    for (int mi = 0; mi < 4; ++mi) {
      int o = m0 + wr * 64 + mi * 16 + r0;
      #pragma unroll
      for (int ni = 0; ni < 4; ++ni) {
        int n = n0 + wc * 64 + ni * 16 + cn;
        #pragma unroll
        for (int r = 0; r < 4; ++r)
          C[(long)(o + r) * ldc + n] = f2b(acc[mi][ni][r]);
      }
    }
  }
}

// ---------------- rowstat: per (b,d) row of k: m = max_n, sinv = 1/sum(exp(k-m)) ----------------
__global__ __launch_bounds__(256) void rowstat_kernel(const unsigned short* __restrict__ kv,
                                                      float* __restrict__ stats) {
  const int row = blockIdx.x;          // 0..4095 = b*512 + d
  const int b = row >> 9, d = row & 511;
  const unsigned short* kp = kv + ((long)b * 1024 + d) * 4096;
  const int tid = threadIdx.x, wave = tid >> 6, lane = tid & 63;
  __shared__ float red[8];

  float v[16];
  u16x8 l0 = *(const u16x8*)(kp + tid * 8);
  u16x8 l1 = *(const u16x8*)(kp + 2048 + tid * 8);
  #pragma unroll
  for (int j = 0; j < 8; ++j) { v[j] = b2f(l0[j]); v[8 + j] = b2f(l1[j]); }

  float m = v[0];
  #pragma unroll
  for (int j = 1; j < 16; ++j) m = fmaxf(m, v[j]);
  #pragma unroll
  for (int off = 32; off > 0; off >>= 1) m = fmaxf(m, __shfl_xor(m, off));
  if (lane == 0) red[wave] = m;
  __syncthreads();
  m = fmaxf(fmaxf(red[0], red[1]), fmaxf(red[2], red[3]));

  float s = 0.f;
  #pragma unroll
  for (int j = 0; j < 16; ++j) s += __expf(v[j] - m);
  #pragma unroll
  for (int off = 32; off > 0; off >>= 1) s += __shfl_xor(s, off);
  if (lane == 0) red[4 + wave] = s;
  __syncthreads();
  if (tid == 0) {
    s = red[4] + red[5] + red[6] + red[7];
    stats[2 * row] = m;
    stats[2 * row + 1] = 1.0f / s;
  }
}

// ---------------- context: ctx_part[s][bh] = softmax(k)|_{n-slice s} @ v^T ----------------
__global__ __launch_bounds__(256) void context_kernel(const unsigned short* __restrict__ kv,
                                                      const float* __restrict__ stats,
                                                      float* __restrict__ ctx_part) {
  const int s = blockIdx.x, bh = blockIdx.y, b = bh >> 3, h = bh & 7;
  const unsigned short* Kp = kv + ((long)b * 1024 + h * 64) * 4096;
  const unsigned short* Vp = kv + ((long)b * 1024 + 512 + h * 64) * 4096;
  const float* sb = stats + ((long)b * 512 + h * 64) * 2;
  const int tid = threadIdx.x, wave = tid >> 6, lane = tid & 63;

  float mrow[4], srow[4];
  #pragma unroll
  for (int mi = 0; mi < 4; ++mi) {
    int rA = mi * 16 + (lane & 15);
    mrow[mi] = sb[2 * rA];
    srow[mi] = sb[2 * rA + 1];
  }

  f32x4 acc[4][4];
  const f32x4 zero = {0.f, 0.f, 0.f, 0.f};
  #pragma unroll
  for (int i = 0; i < 4; ++i)
    #pragma unroll
    for (int j = 0; j < 4; ++j) acc[i][j] = zero;

  const int kbeg = s * 512 + wave * 128;
  for (int k0 = kbeg; k0 < kbeg + 128; k0 += 32) {
    const int kc = k0 + (lane >> 4) * 8;
    bf16x8 a[4], bv[4];
    #pragma unroll
    for (int mi = 0; mi < 4; ++mi) {
      u16x8 kr = *(const u16x8*)(Kp + (long)(mi * 16 + (lane & 15)) * 4096 + kc);
      u16x8 pr;
      #pragma unroll
      for (int j = 0; j < 8; ++j)
        pr[j] = f2b(__expf(b2f(kr[j]) - mrow[mi]) * srow[mi]);
      a[mi] = __builtin_bit_cast(bf16x8, pr);
    }
    #pragma unroll
    for (int ni = 0; ni < 4; ++ni)
      bv[ni] = *(const bf16x8*)(Vp + (long)(ni * 16 + (lane & 15)) * 4096 + kc);
    #pragma unroll
    for (int mi = 0; mi < 4; ++mi)
      #pragma unroll
      for (int ni = 0; ni < 4; ++ni)
        acc[mi][ni] = __builtin_amdgcn_mfma_f32_16x16x32_bf16(a[mi], bv[ni], acc[mi][ni], 0, 0, 0);
  }

  __shared__ float part[4][64][64];  // 64KB
  #pragma unroll
  for (int mi = 0; mi < 4; ++mi)
    #pragma unroll
    for (int ni = 0; ni < 4; ++ni)
      #pragma unroll
      for (int r = 0; r < 4; ++r)
        part[wave][mi * 16 + (lane >> 4) * 4 + r][ni * 16 + (lane & 15)] = acc[mi][ni][r];
  __syncthreads();
  float* cp = ctx_part + ((long)(s * 64 + bh)) * 4096;
  for (int i = tid; i < 4096; i += 256) {
    int dd = i >> 6, ee = i & 63;
    cp[i] = part[0][dd][ee] + part[1][dd][ee] + part[2][dd][ee] + part[3][dd][ee];
  }
}

// ---------------- W2[b][c][h*64+d] = sum_e w_out[c][h*64+e] * (sum_s ctx_part) ----------------
__global__ __launch_bounds__(256) void w2_kernel(const float* __restrict__ ctx_part,
                                                 const float* __restrict__ w_out,
                                                 unsigned short* __restrict__ W2) {
  const int cq = blockIdx.x, bh = blockIdx.y, b = bh >> 3, h = bh & 7;
  __shared__ float cs[64][65];
  const int tid = threadIdx.x;
  for (int i = tid; i < 4096; i += 256) {
    float v = 0.f;
    #pragma unroll
    for (int s = 0; s < 8; ++s) v += ctx_part[((long)(s * 64 + bh)) * 4096 + i];
    cs[i >> 6][i & 63] = v;
  }
  __syncthreads();
  const int c = cq * 128 + (tid & 127);
  const int dbeg = (tid >> 7) * 32;
  const float* wp = w_out + (long)c * 512 + h * 64;
  float wrow[64];
  #pragma unroll
  for (int e = 0; e < 64; ++e) wrow[e] = wp[e];
  unsigned short* W2p = W2 + ((long)b * 512 + c) * 512 + h * 64;
  for (int dd = dbeg; dd < dbeg + 32; ++dd) {
    float s = 0.f;
    #pragma unroll
    for (int e = 0; e < 64; ++e) s = fmaf(wrow[e], cs[dd][e], s);
    W2p[dd] = f2b(s);
  }
}

extern "C" void kernel_launch(void* const* d_in, const int* in_sizes, int n_in,
                              void* d_out, int out_size, void* d_ws, size_t ws_size,
                              hipStream_t stream) {
  const float* x     = (const float*)d_in[0];   // (8, 512, 64, 64)
  const float* w_qkv = (const float*)d_in[1];   // (1536, 512)
  const float* w_out = (const float*)d_in[2];   // (512, 512)
  const float* b_out = (const float*)d_in[3];   // (512,)

  char* ws = (char*)d_ws;
  unsigned short* xT   = (unsigned short*)ws;                   // 8*4096*512*2  = 33,554,432
  unsigned short* kv   = (unsigned short*)(ws + 33554432);      // 8*1024*4096*2 = 67,108,864
  unsigned short* wkv  = (unsigned short*)(ws + 100663296);     // 1024*512*2    =  1,048,576
  unsigned short* WqT  = (unsigned short*)(ws + 101711872);     // 512*512*2     =    524,288
  float*          stats= (float*)(ws + 102236160);              // 4096*2*4      =     32,768
  float*          ctxp = (float*)(ws + 102268928);              // 8*64*4096*4   =  8,388,608
  unsigned short* W2   = (unsigned short*)(ws + 110657536);     // 8*512*512*2   =  4,194,304
  unsigned short* W3   = (unsigned short*)(ws + 114851840);     // 8*512*512*2   =  4,194,304

  prep_wkv_kernel<<<dim3(512), dim3(256), 0, stream>>>(w_qkv, wkv);
  prep_wqT_kernel<<<dim3(8, 8), dim3(256), 0, stream>>>(w_qkv, WqT);
  transpose_x_kernel<<<dim3(64, 8, 8), dim3(256), 0, stream>>>(x, xT);
  // kv = w_qkv[512:1536] @ x  (per batch: 1024x512 @ 512x4096), raw scores bf16
  gemm128_bt<<<dim3(32, 8, 8), dim3(256), 0, stream>>>(
      wkv, 0L, xT, (long)4096 * 512, (void*)kv, (long)1024 * 4096, 4096, (const float*)nullptr);
  rowstat_kernel<<<dim3(4096), dim3(256), 0, stream>>>(kv, stats);
  context_kernel<<<dim3(8, 64), dim3(256), 0, stream>>>(kv, stats, ctxp);
  w2_kernel<<<dim3(4, 64), dim3(256), 0, stream>>>(ctxp, w_out, W2);
  // W3[b] = W2[b] @ Wq  (512x512 @ 512x512), via BT = WqT
  gemm128_bt<<<dim3(4, 4, 8), dim3(256), 0, stream>>>(
      W2, (long)512 * 512, WqT, 0L, (void*)W3, (long)512 * 512, 512, (const float*)nullptr);
  // out = W3 @ x + bias  (per batch: 512x512 @ 512x4096), fp32 out
  gemm128_bt<<<dim3(32, 4, 8), dim3(256), 0, stream>>>(
      W3, (long)512 * 512, xT, (long)4096 * 512, d_out, (long)512 * 4096, 4096, b_out);
}